// Round 2
// baseline (903.178 us; speedup 1.0000x reference)
//
#include <hip/hip_runtime.h>
#include <hip/hip_bf16.h>

#define EMBED 1024
#define NHEADS 16
#define HDIM 64
#define BATCH 4
#define SEQ 2048
#define BT (BATCH*SEQ)      // 8192
#define NQKV (3*EMBED)      // 3072

// I/O is FP32 (reference dtypes). MFMA path uses split-bf16 (hi/lo) with fp32
// accumulate: x = hi + lo, product = Ah*Bh + Ah*Bl + Al*Bh  (3 MFMAs),
// residual ~2e-5 relative -> absmax well under the 5e-3 threshold.
// d_ws usage: 4 * 8388608 floats = 134,217,728 bytes (Q,K,V,attn-out).

typedef __bf16 bf16;
typedef __attribute__((ext_vector_type(8))) __bf16 bf16x8;
typedef __attribute__((ext_vector_type(4))) float f32x4;

__device__ __forceinline__ f32x4 mfma16(bf16x8 a, bf16x8 b, f32x4 c) {
    return __builtin_amdgcn_mfma_f32_16x16x32_bf16(a, b, c, 0, 0, 0);
}

// ---------------------------------------------------------------------------
// Kernel 1: QKV projection GEMM (M=8192, N=3072, K=1024) + bias + RoPE,
// fp32 in/out, split-bf16 MFMA.  64x64 tile, 4 waves (2x2), K-step 32.
// ---------------------------------------------------------------------------
__global__ __launch_bounds__(256) void qkv_rope_kernel(
    const float* __restrict__ X, const float* __restrict__ W,
    const float* __restrict__ bias,
    float* __restrict__ Qw, float* __restrict__ Kw, float* __restrict__ Vw)
{
    __shared__ __align__(16) bf16 Ah[64][40], Al[64][40];  // 80B stride, 16B-align
    __shared__ __align__(16) bf16 Bh[64][40], Bl[64][40];

    const int tid  = threadIdx.x;
    const int m0   = blockIdx.y * 64;
    const int n0   = blockIdx.x * 64;
    const int lane = tid & 63, wv = tid >> 6;
    const int wm = wv >> 1, wn = wv & 1;
    const int quad = lane >> 4, l15 = lane & 15;
    const int lrow = tid >> 2;           // 0..63
    const int lcol = (tid & 3) * 8;      // 0,8,16,24

    f32x4 acc[2][2];
    #pragma unroll
    for (int i = 0; i < 2; i++)
        #pragma unroll
        for (int j = 0; j < 2; j++)
            acc[i][j] = (f32x4){0.f, 0.f, 0.f, 0.f};

    for (int k0 = 0; k0 < EMBED; k0 += 32) {
        const float* xs = X + (size_t)(m0 + lrow) * EMBED + k0 + lcol;
        const float* wsrc = W + (size_t)(n0 + lrow) * EMBED + k0 + lcol;
        float4 a0 = *(const float4*)xs,   a1 = *(const float4*)(xs + 4);
        float4 b0 = *(const float4*)wsrc, b1 = *(const float4*)(wsrc + 4);
        float av[8] = {a0.x,a0.y,a0.z,a0.w,a1.x,a1.y,a1.z,a1.w};
        float bv[8] = {b0.x,b0.y,b0.z,b0.w,b1.x,b1.y,b1.z,b1.w};
        #pragma unroll
        for (int e = 0; e < 8; e++) {
            bf16 h = (bf16)av[e];
            Ah[lrow][lcol+e] = h; Al[lrow][lcol+e] = (bf16)(av[e] - (float)h);
            bf16 g = (bf16)bv[e];
            Bh[lrow][lcol+e] = g; Bl[lrow][lcol+e] = (bf16)(bv[e] - (float)g);
        }
        __syncthreads();
        bf16x8 ah[2], al2[2], bh[2], bl2[2];
        #pragma unroll
        for (int i = 0; i < 2; i++) {
            ah[i]  = *(const bf16x8*)&Ah[wm*32 + i*16 + l15][quad*8];
            al2[i] = *(const bf16x8*)&Al[wm*32 + i*16 + l15][quad*8];
        }
        #pragma unroll
        for (int j = 0; j < 2; j++) {
            bh[j]  = *(const bf16x8*)&Bh[wn*32 + j*16 + l15][quad*8];
            bl2[j] = *(const bf16x8*)&Bl[wn*32 + j*16 + l15][quad*8];
        }
        #pragma unroll
        for (int i = 0; i < 2; i++)
            #pragma unroll
            for (int j = 0; j < 2; j++) {
                acc[i][j] = mfma16(ah[i],  bh[j],  acc[i][j]);
                acc[i][j] = mfma16(ah[i],  bl2[j], acc[i][j]);
                acc[i][j] = mfma16(al2[i], bh[j],  acc[i][j]);
            }
        __syncthreads();
    }

    // Epilogue: bias + RoPE (Q,K) + scatter.  C-layout: row=quad*4+r, col=l15.
    #pragma unroll
    for (int i = 0; i < 2; i++) {
        #pragma unroll
        for (int j = 0; j < 2; j++) {
            const int n    = n0 + wn*32 + j*16 + l15;
            const float bz = bias[n];
            const int sect = n >> 10;            // 0=Q 1=K 2=V; wave-uniform
            const int d    = n & 1023;
            const int h    = d >> 6, hd = d & 63;
            // inv_freq = 10000^(-(hd&~1)/64)
            const float inv = exp2f(-(float)(hd & ~1) * 0.20762051f);
            #pragma unroll
            for (int r = 0; r < 4; r++) {
                const int m = m0 + wm*32 + i*16 + quad*4 + r;
                const int b = m >> 11, t = m & 2047;
                float v = acc[i][j][r] + bz;
                const size_t dst = (((size_t)(b*NHEADS + h) * SEQ + t) << 6) + hd;
                if (sect < 2) {
                    float partner = __shfl_xor(v, 1, 64);
                    float ang = (float)t * inv;
                    float sn, cs;
                    sincosf(ang, &sn, &cs);
                    float o = (hd & 1) ? fmaf(partner, sn, v * cs)
                                       : fmaf(v, cs, -(partner * sn));
                    ((sect == 0) ? Qw : Kw)[dst] = o;
                } else {
                    Vw[dst] = v;
                }
            }
        }
    }
}

// ---------------------------------------------------------------------------
// Kernel 2: flash attention, fp32 in/out, split-bf16 MFMA.  One block per
// (bh, 64 Q rows); each wave owns 16 Q rows.  K/V chunks of 64 staged hi/lo
// in LDS (V transposed).  P tile (hi/lo) aliases the K tiles after a barrier.
// ---------------------------------------------------------------------------
__global__ __launch_bounds__(256) void attn_kernel(
    const float* __restrict__ Qw, const float* __restrict__ Kw,
    const float* __restrict__ Vw, float* __restrict__ Ow)
{
    __shared__ __align__(16) bf16 Qh[64][72], Ql[64][72];
    __shared__ __align__(16) bf16 Kh[64][72], Kl[64][72];   // also P hi/lo
    __shared__ __align__(16) bf16 Vh[64][72], Vl[64][72];   // [dim][key]

    const int tid  = threadIdx.x;
    const int lane = tid & 63, wv = tid >> 6;
    const int quad = lane >> 4, l15 = lane & 15;
    const int bh   = blockIdx.y;
    const int q0   = blockIdx.x * 64;
    const size_t base = (size_t)bh * SEQ * HDIM;

    {   // stage Q tile 64x64 hi/lo (visible after in-loop barriers)
        const int r = tid >> 2, c = (tid & 3) * 16;
        const float* src = Qw + base + (size_t)(q0 + r) * HDIM + c;
        #pragma unroll
        for (int q4 = 0; q4 < 4; q4++) {
            float4 f = *(const float4*)(src + q4*4);
            float vv[4] = {f.x, f.y, f.z, f.w};
            #pragma unroll
            for (int e = 0; e < 4; e++) {
                bf16 h = (bf16)vv[e];
                Qh[r][c + q4*4 + e] = h;
                Ql[r][c + q4*4 + e] = (bf16)(vv[e] - (float)h);
            }
        }
    }

    f32x4 o_acc[4];
    #pragma unroll
    for (int dn = 0; dn < 4; dn++) o_acc[dn] = (f32x4){0.f, 0.f, 0.f, 0.f};
    float m_run[4], l_run[4];
    #pragma unroll
    for (int r = 0; r < 4; r++) { m_run[r] = -3.0e38f; l_run[r] = 0.f; }

    for (int j0 = 0; j0 < SEQ; j0 += 64) {
        __syncthreads();   // prior PV reads complete before restaging
        {   // stage K chunk hi/lo
            const int r = tid >> 2, c = (tid & 3) * 16;
            const float* src = Kw + base + (size_t)(j0 + r) * HDIM + c;
            #pragma unroll
            for (int q4 = 0; q4 < 4; q4++) {
                float4 f = *(const float4*)(src + q4*4);
                float vv[4] = {f.x, f.y, f.z, f.w};
                #pragma unroll
                for (int e = 0; e < 4; e++) {
                    bf16 h = (bf16)vv[e];
                    Kh[r][c + q4*4 + e] = h;
                    Kl[r][c + q4*4 + e] = (bf16)(vv[e] - (float)h);
                }
            }
        }
        {   // stage V chunk transposed hi/lo
            const int j = tid & 63, g = tid >> 6;
            const float* src = Vw + base + (size_t)(j0 + j) * HDIM + g * 16;
            #pragma unroll
            for (int q4 = 0; q4 < 4; q4++) {
                float4 f = *(const float4*)(src + q4*4);
                float vv[4] = {f.x, f.y, f.z, f.w};
                #pragma unroll
                for (int e = 0; e < 4; e++) {
                    const int d = g*16 + q4*4 + e;
                    bf16 h = (bf16)vv[e];
                    Vh[d][j] = h;
                    Vl[d][j] = (bf16)(vv[e] - (float)h);
                }
            }
        }
        __syncthreads();

        // S = Q K^T  (16 rows x 64 keys per wave), split-bf16
        bf16x8 aqh0 = *(const bf16x8*)&Qh[wv*16 + l15][quad*8];
        bf16x8 aqh1 = *(const bf16x8*)&Qh[wv*16 + l15][32 + quad*8];
        bf16x8 aql0 = *(const bf16x8*)&Ql[wv*16 + l15][quad*8];
        bf16x8 aql1 = *(const bf16x8*)&Ql[wv*16 + l15][32 + quad*8];
        f32x4 sacc[4];
        #pragma unroll
        for (int jn = 0; jn < 4; jn++) {
            f32x4 z = (f32x4){0.f, 0.f, 0.f, 0.f};
            bf16x8 kh0 = *(const bf16x8*)&Kh[jn*16 + l15][quad*8];
            bf16x8 kh1 = *(const bf16x8*)&Kh[jn*16 + l15][32 + quad*8];
            bf16x8 kl0 = *(const bf16x8*)&Kl[jn*16 + l15][quad*8];
            bf16x8 kl1 = *(const bf16x8*)&Kl[jn*16 + l15][32 + quad*8];
            z = mfma16(aqh0, kh0, z);  z = mfma16(aqh1, kh1, z);
            z = mfma16(aqh0, kl0, z);  z = mfma16(aqh1, kl1, z);
            z = mfma16(aql0, kh0, z);  z = mfma16(aql1, kh1, z);
            sacc[jn] = z;
        }
        __syncthreads();   // ALL waves done reading K tiles -> P may alias them

        float sv[4][4];
        #pragma unroll
        for (int jn = 0; jn < 4; jn++)
            #pragma unroll
            for (int r = 0; r < 4; r++) sv[jn][r] = sacc[jn][r] * 0.125f;

        // online softmax per row (row = quad*4+r; 16 cols per quad-lane)
        #pragma unroll
        for (int r = 0; r < 4; r++) {
            float mx = fmaxf(fmaxf(sv[0][r], sv[1][r]), fmaxf(sv[2][r], sv[3][r]));
            #pragma unroll
            for (int msk = 1; msk < 16; msk <<= 1) mx = fmaxf(mx, __shfl_xor(mx, msk, 64));
            const float mnew  = fmaxf(m_run[r], mx);
            const float alpha = __expf(m_run[r] - mnew);
            float p[4], lloc = 0.f;
            #pragma unroll
            for (int jn = 0; jn < 4; jn++) { p[jn] = __expf(sv[jn][r] - mnew); lloc += p[jn]; }
            #pragma unroll
            for (int msk = 1; msk < 16; msk <<= 1) lloc += __shfl_xor(lloc, msk, 64);
            l_run[r] = l_run[r] * alpha + lloc;
            m_run[r] = mnew;
            #pragma unroll
            for (int dn = 0; dn < 4; dn++) o_acc[dn][r] *= alpha;
            #pragma unroll
            for (int jn = 0; jn < 4; jn++) {
                bf16 ph = (bf16)p[jn];
                Kh[wv*16 + quad*4 + r][jn*16 + l15] = ph;                      // P hi
                Kl[wv*16 + quad*4 + r][jn*16 + l15] = (bf16)(p[jn] - (float)ph); // P lo
            }
        }
        __syncthreads();   // P writes visible before fragment reads

        // O += P V  (split-bf16)
        bf16x8 aph0 = *(const bf16x8*)&Kh[wv*16 + l15][quad*8];
        bf16x8 aph1 = *(const bf16x8*)&Kh[wv*16 + l15][32 + quad*8];
        bf16x8 apl0 = *(const bf16x8*)&Kl[wv*16 + l15][quad*8];
        bf16x8 apl1 = *(const bf16x8*)&Kl[wv*16 + l15][32 + quad*8];
        #pragma unroll
        for (int dn = 0; dn < 4; dn++) {
            bf16x8 vh0 = *(const bf16x8*)&Vh[dn*16 + l15][quad*8];
            bf16x8 vh1 = *(const bf16x8*)&Vh[dn*16 + l15][32 + quad*8];
            bf16x8 vl0 = *(const bf16x8*)&Vl[dn*16 + l15][quad*8];
            bf16x8 vl1 = *(const bf16x8*)&Vl[dn*16 + l15][32 + quad*8];
            o_acc[dn] = mfma16(aph0, vh0, o_acc[dn]);
            o_acc[dn] = mfma16(aph1, vh1, o_acc[dn]);
            o_acc[dn] = mfma16(aph0, vl0, o_acc[dn]);
            o_acc[dn] = mfma16(aph1, vl1, o_acc[dn]);
            o_acc[dn] = mfma16(apl0, vh0, o_acc[dn]);
            o_acc[dn] = mfma16(apl1, vh1, o_acc[dn]);
        }
    }

    // epilogue: O/l -> attn workspace [b][t][h*64+d] (fp32)
    const int b = bh >> 4, h = bh & 15;
    #pragma unroll
    for (int r = 0; r < 4; r++) {
        const int t = q0 + wv*16 + quad*4 + r;
        const float inv_l = 1.0f / l_run[r];
        #pragma unroll
        for (int dn = 0; dn < 4; dn++)
            Ow[(size_t)(b*SEQ + t) * EMBED + h*HDIM + dn*16 + l15] =
                o_acc[dn][r] * inv_l;
    }
}

// ---------------------------------------------------------------------------
// Kernel 3: out projection GEMM (M=8192, N=1024, K=1024) + bias, fp32 I/O,
// split-bf16 MFMA -> d_out
// ---------------------------------------------------------------------------
__global__ __launch_bounds__(256) void outproj_kernel(
    const float* __restrict__ X, const float* __restrict__ W,
    const float* __restrict__ bias, float* __restrict__ Out)
{
    __shared__ __align__(16) bf16 Ah[64][40], Al[64][40];
    __shared__ __align__(16) bf16 Bh[64][40], Bl[64][40];

    const int tid  = threadIdx.x;
    const int m0   = blockIdx.y * 64;
    const int n0   = blockIdx.x * 64;
    const int lane = tid & 63, wv = tid >> 6;
    const int wm = wv >> 1, wn = wv & 1;
    const int quad = lane >> 4, l15 = lane & 15;
    const int lrow = tid >> 2;
    const int lcol = (tid & 3) * 8;

    f32x4 acc[2][2];
    #pragma unroll
    for (int i = 0; i < 2; i++)
        #pragma unroll
        for (int j = 0; j < 2; j++)
            acc[i][j] = (f32x4){0.f, 0.f, 0.f, 0.f};

    for (int k0 = 0; k0 < EMBED; k0 += 32) {
        const float* xs = X + (size_t)(m0 + lrow) * EMBED + k0 + lcol;
        const float* wsrc = W + (size_t)(n0 + lrow) * EMBED + k0 + lcol;
        float4 a0 = *(const float4*)xs,   a1 = *(const float4*)(xs + 4);
        float4 b0 = *(const float4*)wsrc, b1 = *(const float4*)(wsrc + 4);
        float av[8] = {a0.x,a0.y,a0.z,a0.w,a1.x,a1.y,a1.z,a1.w};
        float bv[8] = {b0.x,b0.y,b0.z,b0.w,b1.x,b1.y,b1.z,b1.w};
        #pragma unroll
        for (int e = 0; e < 8; e++) {
            bf16 h = (bf16)av[e];
            Ah[lrow][lcol+e] = h; Al[lrow][lcol+e] = (bf16)(av[e] - (float)h);
            bf16 g = (bf16)bv[e];
            Bh[lrow][lcol+e] = g; Bl[lrow][lcol+e] = (bf16)(bv[e] - (float)g);
        }
        __syncthreads();
        bf16x8 ah[2], al2[2], bh[2], bl2[2];
        #pragma unroll
        for (int i = 0; i < 2; i++) {
            ah[i]  = *(const bf16x8*)&Ah[wm*32 + i*16 + l15][quad*8];
            al2[i] = *(const bf16x8*)&Al[wm*32 + i*16 + l15][quad*8];
        }
        #pragma unroll
        for (int j = 0; j < 2; j++) {
            bh[j]  = *(const bf16x8*)&Bh[wn*32 + j*16 + l15][quad*8];
            bl2[j] = *(const bf16x8*)&Bl[wn*32 + j*16 + l15][quad*8];
        }
        #pragma unroll
        for (int i = 0; i < 2; i++)
            #pragma unroll
            for (int j = 0; j < 2; j++) {
                acc[i][j] = mfma16(ah[i],  bh[j],  acc[i][j]);
                acc[i][j] = mfma16(ah[i],  bl2[j], acc[i][j]);
                acc[i][j] = mfma16(al2[i], bh[j],  acc[i][j]);
            }
        __syncthreads();
    }

    #pragma unroll
    for (int i = 0; i < 2; i++) {
        #pragma unroll
        for (int j = 0; j < 2; j++) {
            const int n = n0 + wn*32 + j*16 + l15;
            const float bz = bias[n];
            #pragma unroll
            for (int r = 0; r < 4; r++) {
                const int m = m0 + wm*32 + i*16 + quad*4 + r;
                Out[(size_t)m * EMBED + n] = acc[i][j][r] + bz;
            }
        }
    }
}

// ---------------------------------------------------------------------------
extern "C" void kernel_launch(void* const* d_in, const int* in_sizes, int n_in,
                              void* d_out, int out_size, void* d_ws, size_t ws_size,
                              hipStream_t stream)
{
    const float* query = (const float*)d_in[0];
    const float* in_w  = (const float*)d_in[1];
    const float* in_b  = (const float*)d_in[2];
    const float* out_w = (const float*)d_in[3];
    const float* out_b = (const float*)d_in[4];
    float* out = (float*)d_out;

    float* ws = (float*)d_ws;
    const size_t NT = (size_t)BATCH * NHEADS * SEQ * HDIM;  // 8388608
    float* Qw = ws;
    float* Kw = ws + NT;
    float* Vw = ws + 2 * NT;
    float* Aw = ws + 3 * NT;   // attention output [B][T][EMBED]

    dim3 g1(NQKV / 64, BT / 64);   // (48,128)
    qkv_rope_kernel<<<g1, 256, 0, stream>>>(query, in_w, in_b, Qw, Kw, Vw);
    dim3 g2(SEQ / 64, BATCH * NHEADS);  // (32,64)
    attn_kernel<<<g2, 256, 0, stream>>>(Qw, Kw, Vw, Aw);
    dim3 g3(EMBED / 64, BT / 64);  // (16,128)
    outproj_kernel<<<g3, 256, 0, stream>>>(Aw, out_w, out_b, out);
}

// Round 3
// 660.099 us; speedup vs baseline: 1.3682x; 1.3682x over previous
//
#include <hip/hip_runtime.h>
#include <hip/hip_bf16.h>

#define EMBED 1024
#define NHEADS 16
#define HDIM 64
#define BATCH 4
#define SEQ 2048
#define BT (BATCH*SEQ)      // 8192
#define NQKV (3*EMBED)      // 3072

// I/O FP32.  Projections: split-bf16 (hi/lo) MFMA, fp32 accumulate.
// Attention: plain bf16 MFMA (error analysis: probability-weighted averaging
// keeps added absmax ~3-6e-4; measured headroom 9.8e-4 vs 5e-3 threshold).
// QKV kernel writes bf16 Q,K [bh][t][64] (RoPE applied) and bf16 V^T
// [bh][d][t] so the attention hot loop does zero conversion work.

typedef __bf16 bf16;
typedef __attribute__((ext_vector_type(8))) __bf16 bf16x8;
typedef __attribute__((ext_vector_type(4))) float f32x4;

__device__ __forceinline__ f32x4 mfma16(bf16x8 a, bf16x8 b, f32x4 c) {
    return __builtin_amdgcn_mfma_f32_16x16x32_bf16(a, b, c, 0, 0, 0);
}

// ---------------------------------------------------------------------------
// Kernel 1: QKV GEMM (M=8192, N=3072, K=1024) + bias + RoPE, split-bf16.
// Epilogue restages the 64x64 tile through LDS and writes bf16 outputs:
//   sect 0/1 (Q/K): [bh][t][64] row-major;  sect 2 (V): transposed [bh][d][t].
// ---------------------------------------------------------------------------
__global__ __launch_bounds__(256) void qkv_rope_kernel(
    const float* __restrict__ X, const float* __restrict__ W,
    const float* __restrict__ bias,
    bf16* __restrict__ Qg, bf16* __restrict__ Kg, bf16* __restrict__ Vtg)
{
    __shared__ __align__(16) bf16 SM[4][64][40];   // Ah,Al,Bh,Bl; Ep aliases [0..1]
    #define AhS SM[0]
    #define AlS SM[1]
    #define BhS SM[2]
    #define BlS SM[3]

    const int tid  = threadIdx.x;
    const int m0   = blockIdx.y * 64;
    const int n0   = blockIdx.x * 64;
    const int lane = tid & 63, wv = tid >> 6;
    const int wm = wv >> 1, wn = wv & 1;
    const int quad = lane >> 4, l15 = lane & 15;
    const int lrow = tid >> 2;           // 0..63
    const int lcol = (tid & 3) * 8;      // 0,8,16,24

    f32x4 acc[2][2];
    #pragma unroll
    for (int i = 0; i < 2; i++)
        #pragma unroll
        for (int j = 0; j < 2; j++)
            acc[i][j] = (f32x4){0.f, 0.f, 0.f, 0.f};

    for (int k0 = 0; k0 < EMBED; k0 += 32) {
        const float* xs = X + (size_t)(m0 + lrow) * EMBED + k0 + lcol;
        const float* wsrc = W + (size_t)(n0 + lrow) * EMBED + k0 + lcol;
        float4 a0 = *(const float4*)xs,   a1 = *(const float4*)(xs + 4);
        float4 b0 = *(const float4*)wsrc, b1 = *(const float4*)(wsrc + 4);
        float av[8] = {a0.x,a0.y,a0.z,a0.w,a1.x,a1.y,a1.z,a1.w};
        float bv[8] = {b0.x,b0.y,b0.z,b0.w,b1.x,b1.y,b1.z,b1.w};
        #pragma unroll
        for (int e = 0; e < 8; e++) {
            bf16 h = (bf16)av[e];
            AhS[lrow][lcol+e] = h; AlS[lrow][lcol+e] = (bf16)(av[e] - (float)h);
            bf16 g = (bf16)bv[e];
            BhS[lrow][lcol+e] = g; BlS[lrow][lcol+e] = (bf16)(bv[e] - (float)g);
        }
        __syncthreads();
        bf16x8 ah[2], al2[2], bh[2], bl2[2];
        #pragma unroll
        for (int i = 0; i < 2; i++) {
            ah[i]  = *(const bf16x8*)&AhS[wm*32 + i*16 + l15][quad*8];
            al2[i] = *(const bf16x8*)&AlS[wm*32 + i*16 + l15][quad*8];
        }
        #pragma unroll
        for (int j = 0; j < 2; j++) {
            bh[j]  = *(const bf16x8*)&BhS[wn*32 + j*16 + l15][quad*8];
            bl2[j] = *(const bf16x8*)&BlS[wn*32 + j*16 + l15][quad*8];
        }
        #pragma unroll
        for (int i = 0; i < 2; i++)
            #pragma unroll
            for (int j = 0; j < 2; j++) {
                acc[i][j] = mfma16(ah[i],  bh[j],  acc[i][j]);
                acc[i][j] = mfma16(ah[i],  bl2[j], acc[i][j]);
                acc[i][j] = mfma16(al2[i], bh[j],  acc[i][j]);
            }
        __syncthreads();
    }

    // -------- epilogue: bias + RoPE, restage via LDS, bf16 out --------
    const int sect = n0 >> 10;                 // block-uniform: 0=Q 1=K 2=V
    const int h    = (n0 & 1023) >> 6;         // block covers exactly one head
    const int bb   = m0 >> 11, t0 = m0 & 2047; // block-uniform batch / t base
    bf16 (*Ep)[72] = (bf16(*)[72])&SM[0][0][0];   // 9216 B, aliases Ah+Al

    #pragma unroll
    for (int i = 0; i < 2; i++) {
        #pragma unroll
        for (int j = 0; j < 2; j++) {
            const int hd = wn*32 + j*16 + l15;       // 0..63 within head
            const int n  = n0 + hd;
            const float bz = bias[n];
            const float inv = exp2f(-(float)(hd & ~1) * 0.20762051f);
            #pragma unroll
            for (int r = 0; r < 4; r++) {
                const int tl = wm*32 + i*16 + quad*4 + r;   // local t
                float v = acc[i][j][r] + bz;
                if (sect < 2) {
                    float partner = __shfl_xor(v, 1, 64);
                    float ang = (float)(t0 + tl) * inv;
                    float sn, cs;
                    sincosf(ang, &sn, &cs);
                    float o = (hd & 1) ? fmaf(partner, sn, v * cs)
                                       : fmaf(v, cs, -(partner * sn));
                    Ep[tl][hd] = (bf16)o;
                } else {
                    Ep[hd][tl] = (bf16)v;     // transposed for V
                }
            }
        }
    }
    __syncthreads();

    const int orow = tid >> 2, oc = (tid & 3) * 16;
    bf16x8 w0 = *(const bf16x8*)&Ep[orow][oc];
    bf16x8 w1 = *(const bf16x8*)&Ep[orow][oc + 8];
    bf16* dst;
    if (sect == 2) {
        dst = Vtg + ((size_t)((bb*NHEADS + h) * HDIM + orow)) * SEQ + t0 + oc;
    } else {
        bf16* base = (sect == 0) ? Qg : Kg;
        dst = base + ((size_t)((bb*NHEADS + h) * SEQ + t0 + orow)) * HDIM + oc;
    }
    *(bf16x8*)dst = w0;
    *(bf16x8*)(dst + 8) = w1;
}

// ---------------------------------------------------------------------------
// Kernel 2: flash attention, plain bf16 MFMA.  Block = (bh, 128 Q rows);
// 4 waves x 32 rows.  K / V^T chunks of 64 keys staged via b128 copies.
// P tile is wave-private LDS (no barrier between softmax and PV).
// LDS 36864 B -> 4 blocks/CU.
// ---------------------------------------------------------------------------
__global__ __launch_bounds__(256) void attn_kernel(
    const bf16* __restrict__ Qg, const bf16* __restrict__ Kg,
    const bf16* __restrict__ Vtg, float* __restrict__ Ow)
{
    __shared__ __align__(16) bf16 Ks[64][72];
    __shared__ __align__(16) bf16 Vt[64][72];
    __shared__ __align__(16) bf16 Ps[4][32][72];

    const int tid  = threadIdx.x;
    const int lane = tid & 63, wv = tid >> 6;
    const int quad = lane >> 4, l15 = lane & 15;
    const int bh   = blockIdx.y;
    const int q0   = blockIdx.x * 128;
    const bf16* Kb = Kg  + (size_t)bh * SEQ * HDIM;
    const bf16* Vb = Vtg + (size_t)bh * HDIM * SEQ;

    // staging map: consecutive 8 lanes -> consecutive 16B chunks of one row
    const int srow = tid >> 3;         // 0..31
    const int schk = (tid & 7) * 8;    // elem 0..56

    // Q fragments straight from global (read once per block)
    bf16x8 aq[2][2];
    #pragma unroll
    for (int mi = 0; mi < 2; mi++) {
        const bf16* qrow = Qg + (size_t)bh * SEQ * HDIM
                         + (size_t)(q0 + wv*32 + mi*16 + l15) * HDIM + quad*8;
        aq[mi][0] = *(const bf16x8*)qrow;
        aq[mi][1] = *(const bf16x8*)(qrow + 32);
    }

    f32x4 o_acc[2][4];
    #pragma unroll
    for (int mi = 0; mi < 2; mi++)
        #pragma unroll
        for (int dn = 0; dn < 4; dn++) o_acc[mi][dn] = (f32x4){0.f,0.f,0.f,0.f};
    float m_run[2][4], l_run[2][4];
    #pragma unroll
    for (int mi = 0; mi < 2; mi++)
        #pragma unroll
        for (int r = 0; r < 4; r++) { m_run[mi][r] = -3.0e38f; l_run[mi][r] = 0.f; }

    for (int j0 = 0; j0 < SEQ; j0 += 64) {
        __syncthreads();   // prior chunk's K/V reads complete
        *(bf16x8*)&Ks[srow][schk]    = *(const bf16x8*)(Kb + (size_t)(j0+srow)*HDIM + schk);
        *(bf16x8*)&Ks[32+srow][schk] = *(const bf16x8*)(Kb + (size_t)(j0+32+srow)*HDIM + schk);
        *(bf16x8*)&Vt[srow][schk]    = *(const bf16x8*)(Vb + (size_t)srow*SEQ + j0 + schk);
        *(bf16x8*)&Vt[32+srow][schk] = *(const bf16x8*)(Vb + (size_t)(32+srow)*SEQ + j0 + schk);
        __syncthreads();

        // S = Q K^T : 32 rows x 64 keys per wave
        f32x4 sacc[2][4];
        #pragma unroll
        for (int jn = 0; jn < 4; jn++) {
            bf16x8 k0 = *(const bf16x8*)&Ks[jn*16 + l15][quad*8];
            bf16x8 k1 = *(const bf16x8*)&Ks[jn*16 + l15][32 + quad*8];
            #pragma unroll
            for (int mi = 0; mi < 2; mi++) {
                f32x4 z = (f32x4){0.f,0.f,0.f,0.f};
                z = mfma16(aq[mi][0], k0, z);
                z = mfma16(aq[mi][1], k1, z);
                sacc[mi][jn] = z;
            }
        }

        // online softmax (row = quad*4+r within mi-tile; 16 keys per lane grp)
        #pragma unroll
        for (int mi = 0; mi < 2; mi++) {
            #pragma unroll
            for (int r = 0; r < 4; r++) {
                float s0 = sacc[mi][0][r]*0.125f, s1 = sacc[mi][1][r]*0.125f;
                float s2 = sacc[mi][2][r]*0.125f, s3 = sacc[mi][3][r]*0.125f;
                float mx = fmaxf(fmaxf(s0,s1), fmaxf(s2,s3));
                #pragma unroll
                for (int msk = 1; msk < 16; msk <<= 1) mx = fmaxf(mx, __shfl_xor(mx, msk, 64));
                const float mnew  = fmaxf(m_run[mi][r], mx);
                const float alpha = __expf(m_run[mi][r] - mnew);
                float p0 = __expf(s0 - mnew), p1 = __expf(s1 - mnew);
                float p2 = __expf(s2 - mnew), p3 = __expf(s3 - mnew);
                float lloc = (p0 + p1) + (p2 + p3);
                #pragma unroll
                for (int msk = 1; msk < 16; msk <<= 1) lloc += __shfl_xor(lloc, msk, 64);
                l_run[mi][r] = l_run[mi][r] * alpha + lloc;
                m_run[mi][r] = mnew;
                #pragma unroll
                for (int dn = 0; dn < 4; dn++) o_acc[mi][dn][r] *= alpha;
                const int prow = mi*16 + quad*4 + r;
                Ps[wv][prow][ 0 + l15] = (bf16)p0;
                Ps[wv][prow][16 + l15] = (bf16)p1;
                Ps[wv][prow][32 + l15] = (bf16)p2;
                Ps[wv][prow][48 + l15] = (bf16)p3;
            }
        }

        // O += P V  (P is wave-private: wave-local LDS ordering suffices)
        #pragma unroll
        for (int mi = 0; mi < 2; mi++) {
            bf16x8 ap0 = *(const bf16x8*)&Ps[wv][mi*16 + l15][quad*8];
            bf16x8 ap1 = *(const bf16x8*)&Ps[wv][mi*16 + l15][32 + quad*8];
            #pragma unroll
            for (int dn = 0; dn < 4; dn++) {
                bf16x8 v0 = *(const bf16x8*)&Vt[dn*16 + l15][quad*8];
                bf16x8 v1 = *(const bf16x8*)&Vt[dn*16 + l15][32 + quad*8];
                o_acc[mi][dn] = mfma16(ap0, v0, o_acc[mi][dn]);
                o_acc[mi][dn] = mfma16(ap1, v1, o_acc[mi][dn]);
            }
        }
    }

    // epilogue: O / l -> fp32 attn workspace [b][t][h*64+d]
    const int bb = bh >> 4, h = bh & 15;
    #pragma unroll
    for (int mi = 0; mi < 2; mi++) {
        #pragma unroll
        for (int r = 0; r < 4; r++) {
            const int t = q0 + wv*32 + mi*16 + quad*4 + r;
            const float inv_l = 1.0f / l_run[mi][r];
            #pragma unroll
            for (int dn = 0; dn < 4; dn++)
                Ow[(size_t)(bb*SEQ + t) * EMBED + h*HDIM + dn*16 + l15] =
                    o_acc[mi][dn][r] * inv_l;
        }
    }
}

// ---------------------------------------------------------------------------
// Kernel 3: out projection GEMM (M=8192, N=1024, K=1024) + bias, fp32 I/O,
// split-bf16 MFMA -> d_out
// ---------------------------------------------------------------------------
__global__ __launch_bounds__(256) void outproj_kernel(
    const float* __restrict__ X, const float* __restrict__ W,
    const float* __restrict__ bias, float* __restrict__ Out)
{
    __shared__ __align__(16) bf16 Ah[64][40], Al[64][40];
    __shared__ __align__(16) bf16 Bh[64][40], Bl[64][40];

    const int tid  = threadIdx.x;
    const int m0   = blockIdx.y * 64;
    const int n0   = blockIdx.x * 64;
    const int lane = tid & 63, wv = tid >> 6;
    const int wm = wv >> 1, wn = wv & 1;
    const int quad = lane >> 4, l15 = lane & 15;
    const int lrow = tid >> 2;
    const int lcol = (tid & 3) * 8;

    f32x4 acc[2][2];
    #pragma unroll
    for (int i = 0; i < 2; i++)
        #pragma unroll
        for (int j = 0; j < 2; j++)
            acc[i][j] = (f32x4){0.f, 0.f, 0.f, 0.f};

    for (int k0 = 0; k0 < EMBED; k0 += 32) {
        const float* xs = X + (size_t)(m0 + lrow) * EMBED + k0 + lcol;
        const float* wsrc = W + (size_t)(n0 + lrow) * EMBED + k0 + lcol;
        float4 a0 = *(const float4*)xs,   a1 = *(const float4*)(xs + 4);
        float4 b0 = *(const float4*)wsrc, b1 = *(const float4*)(wsrc + 4);
        float av[8] = {a0.x,a0.y,a0.z,a0.w,a1.x,a1.y,a1.z,a1.w};
        float bv[8] = {b0.x,b0.y,b0.z,b0.w,b1.x,b1.y,b1.z,b1.w};
        #pragma unroll
        for (int e = 0; e < 8; e++) {
            bf16 h = (bf16)av[e];
            Ah[lrow][lcol+e] = h; Al[lrow][lcol+e] = (bf16)(av[e] - (float)h);
            bf16 g = (bf16)bv[e];
            Bh[lrow][lcol+e] = g; Bl[lrow][lcol+e] = (bf16)(bv[e] - (float)g);
        }
        __syncthreads();
        bf16x8 ah[2], al2[2], bh[2], bl2[2];
        #pragma unroll
        for (int i = 0; i < 2; i++) {
            ah[i]  = *(const bf16x8*)&Ah[wm*32 + i*16 + l15][quad*8];
            al2[i] = *(const bf16x8*)&Al[wm*32 + i*16 + l15][quad*8];
        }
        #pragma unroll
        for (int j = 0; j < 2; j++) {
            bh[j]  = *(const bf16x8*)&Bh[wn*32 + j*16 + l15][quad*8];
            bl2[j] = *(const bf16x8*)&Bl[wn*32 + j*16 + l15][quad*8];
        }
        #pragma unroll
        for (int i = 0; i < 2; i++)
            #pragma unroll
            for (int j = 0; j < 2; j++) {
                acc[i][j] = mfma16(ah[i],  bh[j],  acc[i][j]);
                acc[i][j] = mfma16(ah[i],  bl2[j], acc[i][j]);
                acc[i][j] = mfma16(al2[i], bh[j],  acc[i][j]);
            }
        __syncthreads();
    }

    #pragma unroll
    for (int i = 0; i < 2; i++) {
        #pragma unroll
        for (int j = 0; j < 2; j++) {
            const int n = n0 + wn*32 + j*16 + l15;
            const float bz = bias[n];
            #pragma unroll
            for (int r = 0; r < 4; r++) {
                const int m = m0 + wm*32 + i*16 + quad*4 + r;
                Out[(size_t)m * EMBED + n] = acc[i][j][r] + bz;
            }
        }
    }
}

// ---------------------------------------------------------------------------
extern "C" void kernel_launch(void* const* d_in, const int* in_sizes, int n_in,
                              void* d_out, int out_size, void* d_ws, size_t ws_size,
                              hipStream_t stream)
{
    const float* query = (const float*)d_in[0];
    const float* in_w  = (const float*)d_in[1];
    const float* in_b  = (const float*)d_in[2];
    const float* out_w = (const float*)d_in[3];
    const float* out_b = (const float*)d_in[4];
    float* out = (float*)d_out;

    const size_t NT = (size_t)BATCH * NHEADS * SEQ * HDIM;  // 8388608
    char* ws = (char*)d_ws;
    bf16*  Qg  = (bf16*)ws;                         // NT bf16
    bf16*  Kg  = (bf16*)(ws + 2*NT);                // NT bf16
    bf16*  Vtg = (bf16*)(ws + 4*NT);                // NT bf16 (transposed)
    float* Aw  = (float*)(ws + 6*NT);               // NT fp32

    dim3 g1(NQKV / 64, BT / 64);        // (48,128)
    qkv_rope_kernel<<<g1, 256, 0, stream>>>(query, in_w, in_b, Qg, Kg, Vtg);
    dim3 g2(SEQ / 128, BATCH * NHEADS); // (16,64)
    attn_kernel<<<g2, 256, 0, stream>>>(Qg, Kg, Vtg, Aw);
    dim3 g3(EMBED / 64, BT / 64);       // (16,128)
    outproj_kernel<<<g3, 256, 0, stream>>>(Aw, out_w, out_b, out);
}